// Round 1
// baseline (40.754 us; speedup 1.0000x reference)
//
#include <hip/hip_runtime.h>

// SoftmaxPooling2d: x (32,128,112,112) f32 -> out (32,128,56,56) f32
// 2x2 non-overlapping windows, softmax(beta=1) over the 4 window values,
// weighted sum. Memory-bound: each input element read exactly once.
//
// Layout: thread t handles 2 adjacent output cols (one float4 per input row,
// two rows). 28 threads per (n,c,ho) output row.
//   wp  = t % 28        -> pair index along output row (covers wo = 2wp, 2wp+1)
//   row = t / 28        -> flattened (n*C + c)*56 + ho
// Input addr: base(nc) + (2*ho)*112 + 4*wp   (float4-aligned: 448B row pitch)
// Output addr: base(nc) + ho*56 + 2*wp       (float2-aligned)

#define C_IN   128
#define H_IN   112
#define W_IN   112
#define H_OUT  56
#define W_OUT  56
#define PAIRS_PER_ROW 28   // W_OUT/2

__device__ __forceinline__ float pool4(float a, float b, float c, float d) {
    // softmax-weighted sum of {a,b,c,d}
    float m  = fmaxf(fmaxf(a, b), fmaxf(c, d));
    float ea = __expf(a - m);
    float eb = __expf(b - m);
    float ec = __expf(c - m);
    float ed = __expf(d - m);
    float s  = ea + eb + ec + ed;
    float w  = ea * a + eb * b;
    w = fmaf(ec, c, w);
    w = fmaf(ed, d, w);
    return w / s;
}

__global__ void __launch_bounds__(256)
softmax_pool2d_kernel(const float* __restrict__ in, float* __restrict__ out,
                      unsigned int total_pairs) {
    unsigned int t = blockIdx.x * blockDim.x + threadIdx.x;
    if (t >= total_pairs) return;

    unsigned int wp  = t % PAIRS_PER_ROW;
    unsigned int row = t / PAIRS_PER_ROW;      // (n*C+c)*H_OUT + ho
    unsigned int ho  = row % H_OUT;
    unsigned int nc  = row / H_OUT;

    const float* base = in + (size_t)nc * (H_IN * W_IN)
                           + (size_t)(2u * ho) * W_IN
                           + 4u * wp;
    float4 r0 = *reinterpret_cast<const float4*>(base);
    float4 r1 = *reinterpret_cast<const float4*>(base + W_IN);

    float2 o;
    o.x = pool4(r0.x, r0.y, r1.x, r1.y);
    o.y = pool4(r0.z, r0.w, r1.z, r1.w);

    float* obase = out + (size_t)nc * (H_OUT * W_OUT)
                       + (size_t)ho * W_OUT
                       + 2u * wp;
    *reinterpret_cast<float2*>(obase) = o;
}

extern "C" void kernel_launch(void* const* d_in, const int* in_sizes, int n_in,
                              void* d_out, int out_size, void* d_ws, size_t ws_size,
                              hipStream_t stream) {
    const float* x = (const float*)d_in[0];
    float* out = (float*)d_out;

    // total output elements = out_size; each thread makes 2 of them
    unsigned int total_pairs = (unsigned int)(out_size / 2);   // 6,422,528
    unsigned int block = 256;
    unsigned int grid = (total_pairs + block - 1) / block;     // 25088

    softmax_pool2d_kernel<<<grid, block, 0, stream>>>(x, out, total_pairs);
}